// Round 7
// baseline (92.395 us; speedup 1.0000x reference)
//
#include <hip/hip_runtime.h>

#define NN 256
#define XPW 8          // pairs (x values) per wave
#define RING_D 3       // prefetch depth (pairs in flight)

// hard-coded CG constants (l<=2), float32
#define C13  0.5773502691896258f
#define C15  0.4472135954999579f
#define CC12 0.7071067811865476f
#define S35  0.7745966692414834f
#define S310 0.5477225575051661f
#define C110 0.3162277660168379f
#define S25  0.6324555320336759f
#define S23  0.8164965809277260f
#define C16  0.4082482904638630f
#define S27  0.5345224838248488f
#define S37  0.6546536707079771f
#define C114 0.2672612419124244f

#define CGREL(mx, sv, r0, r1, r2) \
    r0[0] = mx[0]*sv[0]; \
    r0[1] = C13*(mx[1]*sv[3] - mx[2]*sv[2] + mx[3]*sv[1]); \
    r0[2] = C15*(mx[4]*sv[8] - mx[5]*sv[7] + mx[6]*sv[6] - mx[7]*sv[5] + mx[8]*sv[4]); \
    r1[0][0] = mx[0]*sv[1]; r1[1][0] = mx[0]*sv[2]; r1[2][0] = mx[0]*sv[3]; \
    r1[0][1] = mx[1]*sv[0]; r1[1][1] = mx[2]*sv[0]; r1[2][1] = mx[3]*sv[0]; \
    r1[0][2] = CC12*(mx[2]*sv[1] - mx[1]*sv[2]); \
    r1[1][2] = CC12*(mx[3]*sv[1] - mx[1]*sv[3]); \
    r1[2][2] = CC12*(mx[3]*sv[2] - mx[2]*sv[3]); \
    r1[0][3] = S35*mx[3]*sv[4] - S310*mx[2]*sv[5] + C110*mx[1]*sv[6]; \
    r1[1][3] = S310*(mx[3]*sv[5] + mx[1]*sv[7]) - S25*mx[2]*sv[6]; \
    r1[2][3] = S35*mx[1]*sv[8] - S310*mx[2]*sv[7] + C110*mx[3]*sv[6]; \
    r1[0][4] = C110*mx[6]*sv[1] - S310*mx[5]*sv[2] + S35*mx[4]*sv[3]; \
    r1[1][4] = S310*(mx[7]*sv[1] + mx[5]*sv[3]) - S25*mx[6]*sv[2]; \
    r1[2][4] = S35*mx[8]*sv[1] - S310*mx[7]*sv[2] + C110*mx[6]*sv[3]; \
    r1[0][5] = C15*(mx[7]*sv[4] - mx[4]*sv[7]) + S310*(mx[5]*sv[6] - mx[6]*sv[5]); \
    r1[1][5] = S25*(mx[8]*sv[4] - mx[4]*sv[8]) + C110*(mx[5]*sv[7] - mx[7]*sv[5]); \
    r1[2][5] = C15*(mx[8]*sv[5] - mx[5]*sv[8]) + S310*(mx[6]*sv[7] - mx[7]*sv[6]); \
    r2[0][0]=mx[0]*sv[4]; r2[1][0]=mx[0]*sv[5]; r2[2][0]=mx[0]*sv[6]; r2[3][0]=mx[0]*sv[7]; r2[4][0]=mx[0]*sv[8]; \
    r2[0][1] = mx[1]*sv[1]; \
    r2[1][1] = CC12*(mx[2]*sv[1] + mx[1]*sv[2]); \
    r2[2][1] = C16*(mx[3]*sv[1] + mx[1]*sv[3]) + S23*mx[2]*sv[2]; \
    r2[3][1] = CC12*(mx[3]*sv[2] + mx[2]*sv[3]); \
    r2[4][1] = mx[3]*sv[3]; \
    r2[0][2] = S23*mx[2]*sv[4] - C13*mx[1]*sv[5]; \
    r2[1][2] = C13*mx[3]*sv[4] + C16*mx[2]*sv[5] - CC12*mx[1]*sv[6]; \
    r2[2][2] = CC12*(mx[3]*sv[5] - mx[1]*sv[7]); \
    r2[3][2] = CC12*mx[3]*sv[6] - C16*mx[2]*sv[7] - C13*mx[1]*sv[8]; \
    r2[4][2] = C13*mx[3]*sv[7] - S23*mx[2]*sv[8]; \
    r2[0][3]=mx[4]*sv[0]; r2[1][3]=mx[5]*sv[0]; r2[2][3]=mx[6]*sv[0]; r2[3][3]=mx[7]*sv[0]; r2[4][3]=mx[8]*sv[0]; \
    r2[0][4] = C13*mx[5]*sv[1] - S23*mx[4]*sv[2]; \
    r2[1][4] = CC12*mx[6]*sv[1] - C16*mx[5]*sv[2] - C13*mx[4]*sv[3]; \
    r2[2][4] = CC12*(mx[7]*sv[1] - mx[5]*sv[3]); \
    r2[3][4] = C13*mx[8]*sv[1] + C16*mx[7]*sv[2] - CC12*mx[6]*sv[3]; \
    r2[4][4] = S23*mx[8]*sv[2] - C13*mx[7]*sv[3]; \
    r2[0][5] = S27*(mx[4]*sv[6] + mx[6]*sv[4]) - S37*mx[5]*sv[5]; \
    r2[1][5] = S37*(mx[4]*sv[7] + mx[7]*sv[4]) - C114*(mx[5]*sv[6] + mx[6]*sv[5]); \
    r2[2][5] = S27*(mx[8]*sv[4] + mx[4]*sv[8] - mx[6]*sv[6]) + C114*(mx[7]*sv[5] + mx[5]*sv[7]); \
    r2[3][5] = S37*(mx[8]*sv[5] + mx[5]*sv[8]) - C114*(mx[7]*sv[6] + mx[6]*sv[7]); \
    r2[4][5] = S27*(mx[8]*sv[6] + mx[6]*sv[8]) - S37*mx[7]*sv[7];

// ---- async global->LDS dword copy (per-lane gptr; lds dest = base+lane*4) --
typedef __attribute__((address_space(3))) unsigned       lds_u32_t;
typedef __attribute__((address_space(1))) const unsigned glb_u32_t;
__device__ __forceinline__ void gld4(const float* g, float* l){
  __builtin_amdgcn_global_load_lds((glb_u32_t*)g, (lds_u32_t*)l, 4, 0, 0);
}

// ---------------- kernel A: vmp + node-CG + wn mix -> mixed[256][72] -------
__global__ __launch_bounds__(256) void k_nodes(
                        const float* __restrict__ adj,
                        const float* __restrict__ v0,
                        const float* __restrict__ v1,
                        const float* __restrict__ v2,
                        const float* __restrict__ wn0,
                        const float* __restrict__ wn1,
                        const float* __restrict__ wn2,
                        float* __restrict__ mixed){
  __shared__ float part[4][72];
  int i = blockIdx.x;
  int tid = threadIdx.x, wv = tid >> 6, lane = tid & 63;
  {
    const float* vp1; int st1;
    if (lane < 8)       { vp1 = v0 + lane;      st1 = 8;  }
    else if (lane < 32) { vp1 = v1 + (lane-8);  st1 = 24; }
    else                { vp1 = v2 + (lane-32); st1 = 40; }
    const float* vp2 = v2 + 32 + lane;
    const float* arow = adj + i*NN;
    int j0 = wv*64;
    float a1a = 0.f, a1b = 0.f, a2a = 0.f, a2b = 0.f;
    #pragma unroll 8
    for (int j = j0; j < j0+64; j += 2){
      float av0 = arow[j], av1 = arow[j+1];
      a1a = fmaf(av0, vp1[j*st1], a1a);
      a1b = fmaf(av1, vp1[(j+1)*st1], a1b);
      if (lane < 8){
        a2a = fmaf(av0, vp2[j*40], a2a);
        a2b = fmaf(av1, vp2[(j+1)*40], a2b);
      }
    }
    part[wv][lane] = a1a + a1b;
    if (lane < 8) part[wv][64+lane] = a2a + a2b;
  }
  __syncthreads();
  if (wv) return;
  {
    float s = part[0][lane] + part[1][lane] + part[2][lane] + part[3][lane];
    float s2 = 0.f;
    if (lane < 8)
      s2 = part[0][64+lane] + part[1][64+lane] + part[2][64+lane] + part[3][64+lane];
    part[0][lane] = s;
    if (lane < 8) part[0][64+lane] = s2;
  }
  int c = lane >> 3, d = lane & 7;
  float mx[9], sv[9];
  #pragma unroll
  for (int j=0;j<9;j++){ mx[j] = part[0][j*8 + c]; sv[j] = part[0][j*8 + d]; }
  float r0[3], r1[3][6], r2[5][6];
  CGREL(mx, sv, r0, r1, r2)

  float a0[8], a1m[3][8], a2m[5][8];
  #pragma unroll
  for (int dp=0;dp<8;dp++){ a0[dp]=0.f;
    #pragma unroll
    for (int M=0;M<3;M++) a1m[M][dp]=0.f;
    #pragma unroll
    for (int M=0;M<5;M++) a2m[M][dp]=0.f;
  }
  #pragma unroll
  for (int k=0;k<3;k++){
    const float* row = wn0 + (k*64 + lane)*8;
    float4 u = *(const float4*)row;
    float4 v = *(const float4*)(row+4);
    float u8[8] = {u.x,u.y,u.z,u.w,v.x,v.y,v.z,v.w};
    #pragma unroll
    for (int dp=0;dp<8;dp++) a0[dp] = fmaf(r0[k], u8[dp], a0[dp]);
  }
  #pragma unroll
  for (int k=0;k<6;k++){
    const float* row = wn1 + (k*64 + lane)*8;
    float4 u = *(const float4*)row;
    float4 v = *(const float4*)(row+4);
    float u8[8] = {u.x,u.y,u.z,u.w,v.x,v.y,v.z,v.w};
    #pragma unroll
    for (int M=0;M<3;M++)
      #pragma unroll
      for (int dp=0;dp<8;dp++) a1m[M][dp] = fmaf(r1[M][k], u8[dp], a1m[M][dp]);
  }
  #pragma unroll
  for (int k=0;k<6;k++){
    const float* row = wn2 + (k*64 + lane)*8;
    float4 u = *(const float4*)row;
    float4 v = *(const float4*)(row+4);
    float u8[8] = {u.x,u.y,u.z,u.w,v.x,v.y,v.z,v.w};
    #pragma unroll
    for (int M=0;M<5;M++)
      #pragma unroll
      for (int dp=0;dp<8;dp++) a2m[M][dp] = fmaf(r2[M][k], u8[dp], a2m[M][dp]);
  }
  #pragma unroll
  for (int m=0;m<9;m++){
    #pragma unroll
    for (int dp=0;dp<8;dp++){
      float val = (m==0) ? a0[dp] : (m<4 ? a1m[m-1][dp] : a2m[m-4][dp]);
      val += __shfl_xor(val, 1);
      val += __shfl_xor(val, 2);
      val += __shfl_xor(val, 4);
      val += __shfl_xor(val, 8);
      val += __shfl_xor(val, 16);
      val += __shfl_xor(val, 32);
      if (lane == ((m*8+dp) & 63)) mixed[i*72 + m*8 + dp] = val;
    }
  }
}

// ---------------- kernel B: async-LDS pipelined pair kernel ----------------
// Per-wave LDS region (floats):
//   ring  [0, 2880)        : RING_D=3 slots x 960 (wr0|wr1|wr2 per pair)
//   mixed [2880, 3456)     : XPW=8 rows x 72
//   s0    [3456, 3520)     : slot i   (64-slot buffer, 8 used)
//   s1    [3520, 3584)     : slot i*3+j (24 used)
//   s2    [3584, 3648)     : slot i*5+j (40 used)
#define WAVE_F 3648

__device__ __forceinline__ void prefetch_pair(
    int x, int y, int lane,
    const float* __restrict__ wr0, const float* __restrict__ wr1,
    const float* __restrict__ wr2, float* slotp){
  int pxy = x*NN + y;
  const float* g0 = wr0 + (size_t)pxy*192 + lane;
  const float* g1 = wr1 + (size_t)pxy*384 + lane;
  const float* g2 = wr2 + (size_t)pxy*384 + lane;
  #pragma unroll
  for (int k=0;k<3;k++) gld4(g0 + k*64, slotp + k*64);
  #pragma unroll
  for (int k=0;k<6;k++) gld4(g1 + k*64, slotp + 192 + k*64);
  #pragma unroll
  for (int k=0;k<6;k++) gld4(g2 + k*64, slotp + 576 + k*64);
}

// consume one pair: plain C++ LDS reads (ordered after the vmcnt asm by the
// "memory" clobber; aliasing with the prefetch intrinsic keeps issue order).
#define CONSUME(iIdx, slotIdx) { \
  const float* slotp = Lw + (slotIdx)*960; \
  float w0v[3], w1v[6], w2v[6]; \
  _Pragma("unroll") for (int k=0;k<3;k++) w0v[k] = slotp[k*64 + lane]; \
  _Pragma("unroll") for (int k=0;k<6;k++) w1v[k] = slotp[192 + k*64 + lane]; \
  _Pragma("unroll") for (int k=0;k<6;k++) w2v[k] = slotp[576 + k*64 + lane]; \
  const float* mixp = Lw + 2880 + (iIdx)*72; \
  float mx[9], sv[9]; \
  _Pragma("unroll") for (int j=0;j<9;j++) mx[j] = mixp[j*8 + cgp]; \
  sv[0] = Lw[3456 + (iIdx)]; \
  _Pragma("unroll") for (int j=0;j<3;j++) sv[1+j] = Lw[3520 + (iIdx)*3 + j]; \
  _Pragma("unroll") for (int j=0;j<5;j++) sv[4+j] = Lw[3584 + (iIdx)*5 + j]; \
  float r0[3], r1[3][6], r2[5][6]; \
  CGREL(mx, sv, r0, r1, r2) \
  _Pragma("unroll") for (int k=0;k<3;k++) acc[0] = fmaf(r0[k], w0v[k], acc[0]); \
  _Pragma("unroll") for (int k=0;k<6;k++){ \
    acc[1] = fmaf(r1[0][k], w1v[k], acc[1]); \
    acc[2] = fmaf(r1[1][k], w1v[k], acc[2]); \
    acc[3] = fmaf(r1[2][k], w1v[k], acc[3]); \
    acc[4] = fmaf(r2[0][k], w2v[k], acc[4]); \
    acc[5] = fmaf(r2[1][k], w2v[k], acc[5]); \
    acc[6] = fmaf(r2[2][k], w2v[k], acc[6]); \
    acc[7] = fmaf(r2[3][k], w2v[k], acc[7]); \
    acc[8] = fmaf(r2[4][k], w2v[k], acc[8]); } }

#define WAITVM(n) { \
  asm volatile("s_waitcnt vmcnt(" #n ")" ::: "memory"); \
  __builtin_amdgcn_sched_barrier(0); }

__global__ __launch_bounds__(256) void k_pair(
    const float* __restrict__ mixed,
    const float* __restrict__ s0, const float* __restrict__ s1, const float* __restrict__ s2,
    const float* __restrict__ wr0, const float* __restrict__ wr1, const float* __restrict__ wr2,
    float* __restrict__ vsum){
  __shared__ float L[4][WAVE_F];
  int tid = threadIdx.x;
  int lane = tid & 63;
  int wv = tid >> 6;
  int w = blockIdx.x*4 + wv;
  int y = w & (NN-1);
  int xbase = (w >> 8) * XPW;
  int cgp = lane >> 3;
  float* Lw = &L[wv][0];

  // ---- prologue: stage mixed rows + s values + first RING_D pairs --------
  {
    // mixed: 8 rows x 72 = 576 floats = 9 dword instrs
    #pragma unroll
    for (int t=0;t<9;t++)
      gld4(mixed + xbase*72 + t*64 + lane, Lw + 2880 + t*64);
    // s0: slot i = value for pair i (lanes >=8 write dups to slots 8..63)
    gld4(s0 + (xbase + (lane & 7))*NN + y, Lw + 3456);
    // s1: slot i*3+j
    { int e = lane < 24 ? lane : 23; int si = e/3, sj = e - si*3;
      gld4(s1 + ((size_t)((xbase+si)*NN + y))*3 + sj, Lw + 3520); }
    // s2: slot i*5+j
    { int e = lane < 40 ? lane : 39; int si = e/5, sj = e - si*5;
      gld4(s2 + ((size_t)((xbase+si)*NN + y))*5 + sj, Lw + 3584); }
    // first RING_D pairs
    #pragma unroll
    for (int p=0;p<RING_D;p++)
      prefetch_pair(xbase + p, y, lane, wr0, wr1, wr2, Lw + p*960);
  }

  float acc[9];
  #pragma unroll
  for (int m=0;m<9;m++) acc[m]=0.f;

  // ---- main loop: 57 issued; vmcnt(30) => staging + pair i complete ------
  int slot = 0;
  for (int i=0;i<XPW-2;i++){
    WAITVM(30)
    CONSUME(i, slot);
    if (i < XPW-RING_D)
      prefetch_pair(xbase + i + RING_D, y, lane, wr0, wr1, wr2, Lw + slot*960);
    slot = (slot == RING_D-1) ? 0 : slot+1;
  }
  WAITVM(15)
  CONSUME(XPW-2, slot);
  slot = (slot == RING_D-1) ? 0 : slot+1;
  WAITVM(0)
  CONSUME(XPW-1, slot);

  // ---- reduce over cgp groups, atomic into vsum --------------------------
  #pragma unroll
  for (int m=0;m<9;m++){
    float v = acc[m];
    v += __shfl_xor(v, 8);
    v += __shfl_xor(v, 16);
    v += __shfl_xor(v, 32);
    acc[m] = v;
  }
  if (lane < 8){
    #pragma unroll
    for (int m=0;m<9;m++) atomicAdd(&vsum[y*72 + m*8 + lane], acc[m]);
  }
}

// ---------------- kernel C: part sums + normalize + write ------------------
__global__ void k_final(const float* __restrict__ vsum, float* __restrict__ out){
  __shared__ float ps[3];
  int t = threadIdx.x;   // 1024 threads; 18 elements each
  if (t < 3) ps[t] = 0.f;
  __syncthreads();
  float vals[18];
  float p0=0.f, p1=0.f, p2=0.f;
  #pragma unroll
  for (int k=0;k<18;k++){
    int idx = t*18 + k;
    float v = vsum[idx];
    vals[k] = v;
    int mall = (idx >> 3) % 9;
    if (mall == 0) p0 += v; else if (mall < 4) p1 += v; else p2 += v;
  }
  #pragma unroll
  for (int s=1; s<64; s<<=1){
    p0 += __shfl_xor(p0, s);
    p1 += __shfl_xor(p1, s);
    p2 += __shfl_xor(p2, s);
  }
  if ((t & 63) == 0){
    atomicAdd(&ps[0], p0);
    atomicAdd(&ps[1], p1);
    atomicAdd(&ps[2], p2);
  }
  __syncthreads();
  float q0 = ps[0], q1 = ps[1], q2 = ps[2];
  #pragma unroll
  for (int k=0;k<18;k++){
    int idx = t*18 + k;
    int mall = (idx >> 3) % 9;
    float den = (mall == 0) ? q0 : (mall < 4 ? q1 : q2);
    out[idx] = vals[k] / den;
  }
}

extern "C" void kernel_launch(void* const* d_in, const int* in_sizes, int n_in,
                              void* d_out, int out_size, void* d_ws, size_t ws_size,
                              hipStream_t stream) {
  const float* v0  = (const float*)d_in[0];
  const float* v1  = (const float*)d_in[1];
  const float* v2  = (const float*)d_in[2];
  const float* adj = (const float*)d_in[3];
  const float* s0  = (const float*)d_in[4];
  const float* s1  = (const float*)d_in[5];
  const float* s2  = (const float*)d_in[6];
  const float* wn0 = (const float*)d_in[7];
  const float* wn1 = (const float*)d_in[8];
  const float* wn2 = (const float*)d_in[9];
  const float* wr0 = (const float*)d_in[10];
  const float* wr1 = (const float*)d_in[11];
  const float* wr2 = (const float*)d_in[12];
  float* out = (float*)d_out;

  float* ws    = (float*)d_ws;
  float* mixed = ws;            // 18432
  float* vsum  = ws + 18432;    // 18432

  hipMemsetAsync(vsum, 0, 18432*sizeof(float), stream);
  k_nodes<<<NN, 256, 0, stream>>>(adj, v0, v1, v2, wn0, wn1, wn2, mixed);
  k_pair<<<NN*(NN/XPW)/4, 256, 0, stream>>>(mixed, s0, s1, s2, wr0, wr1, wr2, vsum);
  k_final<<<1, 1024, 0, stream>>>(vsum, out);
}

// Round 9
// 87.601 us; speedup vs baseline: 1.0547x; 1.0547x over previous
//
#include <hip/hip_runtime.h>

#define NN 256
#define XPW 8          // pairs (x values) per wave
#define RING_D 2       // prefetch depth (pairs in flight)

// hard-coded CG constants (l<=2), float32
#define C13  0.5773502691896258f
#define C15  0.4472135954999579f
#define CC12 0.7071067811865476f
#define S35  0.7745966692414834f
#define S310 0.5477225575051661f
#define C110 0.3162277660168379f
#define S25  0.6324555320336759f
#define S23  0.8164965809277260f
#define C16  0.4082482904638630f
#define S27  0.5345224838248488f
#define S37  0.6546536707079771f
#define C114 0.2672612419124244f

#define CGREL(mx, sv, r0, r1, r2) \
    r0[0] = mx[0]*sv[0]; \
    r0[1] = C13*(mx[1]*sv[3] - mx[2]*sv[2] + mx[3]*sv[1]); \
    r0[2] = C15*(mx[4]*sv[8] - mx[5]*sv[7] + mx[6]*sv[6] - mx[7]*sv[5] + mx[8]*sv[4]); \
    r1[0][0] = mx[0]*sv[1]; r1[1][0] = mx[0]*sv[2]; r1[2][0] = mx[0]*sv[3]; \
    r1[0][1] = mx[1]*sv[0]; r1[1][1] = mx[2]*sv[0]; r1[2][1] = mx[3]*sv[0]; \
    r1[0][2] = CC12*(mx[2]*sv[1] - mx[1]*sv[2]); \
    r1[1][2] = CC12*(mx[3]*sv[1] - mx[1]*sv[3]); \
    r1[2][2] = CC12*(mx[3]*sv[2] - mx[2]*sv[3]); \
    r1[0][3] = S35*mx[3]*sv[4] - S310*mx[2]*sv[5] + C110*mx[1]*sv[6]; \
    r1[1][3] = S310*(mx[3]*sv[5] + mx[1]*sv[7]) - S25*mx[2]*sv[6]; \
    r1[2][3] = S35*mx[1]*sv[8] - S310*mx[2]*sv[7] + C110*mx[3]*sv[6]; \
    r1[0][4] = C110*mx[6]*sv[1] - S310*mx[5]*sv[2] + S35*mx[4]*sv[3]; \
    r1[1][4] = S310*(mx[7]*sv[1] + mx[5]*sv[3]) - S25*mx[6]*sv[2]; \
    r1[2][4] = S35*mx[8]*sv[1] - S310*mx[7]*sv[2] + C110*mx[6]*sv[3]; \
    r1[0][5] = C15*(mx[7]*sv[4] - mx[4]*sv[7]) + S310*(mx[5]*sv[6] - mx[6]*sv[5]); \
    r1[1][5] = S25*(mx[8]*sv[4] - mx[4]*sv[8]) + C110*(mx[5]*sv[7] - mx[7]*sv[5]); \
    r1[2][5] = C15*(mx[8]*sv[5] - mx[5]*sv[8]) + S310*(mx[6]*sv[7] - mx[7]*sv[6]); \
    r2[0][0]=mx[0]*sv[4]; r2[1][0]=mx[0]*sv[5]; r2[2][0]=mx[0]*sv[6]; r2[3][0]=mx[0]*sv[7]; r2[4][0]=mx[0]*sv[8]; \
    r2[0][1] = mx[1]*sv[1]; \
    r2[1][1] = CC12*(mx[2]*sv[1] + mx[1]*sv[2]); \
    r2[2][1] = C16*(mx[3]*sv[1] + mx[1]*sv[3]) + S23*mx[2]*sv[2]; \
    r2[3][1] = CC12*(mx[3]*sv[2] + mx[2]*sv[3]); \
    r2[4][1] = mx[3]*sv[3]; \
    r2[0][2] = S23*mx[2]*sv[4] - C13*mx[1]*sv[5]; \
    r2[1][2] = C13*mx[3]*sv[4] + C16*mx[2]*sv[5] - CC12*mx[1]*sv[6]; \
    r2[2][2] = CC12*(mx[3]*sv[5] - mx[1]*sv[7]); \
    r2[3][2] = CC12*mx[3]*sv[6] - C16*mx[2]*sv[7] - C13*mx[1]*sv[8]; \
    r2[4][2] = C13*mx[3]*sv[7] - S23*mx[2]*sv[8]; \
    r2[0][3]=mx[4]*sv[0]; r2[1][3]=mx[5]*sv[0]; r2[2][3]=mx[6]*sv[0]; r2[3][3]=mx[7]*sv[0]; r2[4][3]=mx[8]*sv[0]; \
    r2[0][4] = C13*mx[5]*sv[1] - S23*mx[4]*sv[2]; \
    r2[1][4] = CC12*mx[6]*sv[1] - C16*mx[5]*sv[2] - C13*mx[4]*sv[3]; \
    r2[2][4] = CC12*(mx[7]*sv[1] - mx[5]*sv[3]); \
    r2[3][4] = C13*mx[8]*sv[1] + C16*mx[7]*sv[2] - CC12*mx[6]*sv[3]; \
    r2[4][4] = S23*mx[8]*sv[2] - C13*mx[7]*sv[3]; \
    r2[0][5] = S27*(mx[4]*sv[6] + mx[6]*sv[4]) - S37*mx[5]*sv[5]; \
    r2[1][5] = S37*(mx[4]*sv[7] + mx[7]*sv[4]) - C114*(mx[5]*sv[6] + mx[6]*sv[5]); \
    r2[2][5] = S27*(mx[8]*sv[4] + mx[4]*sv[8] - mx[6]*sv[6]) + C114*(mx[7]*sv[5] + mx[5]*sv[7]); \
    r2[3][5] = S37*(mx[8]*sv[5] + mx[5]*sv[8]) - C114*(mx[7]*sv[6] + mx[6]*sv[7]); \
    r2[4][5] = S27*(mx[8]*sv[6] + mx[6]*sv[8]) - S37*mx[7]*sv[7];

// ---- async global->LDS copies; lds dest = uniform base + lane*size --------
typedef __attribute__((address_space(3))) unsigned       lds_u32_t;
typedef __attribute__((address_space(1))) const unsigned glb_u32_t;
__device__ __forceinline__ void gld4(const float* g, float* l){
  __builtin_amdgcn_global_load_lds((glb_u32_t*)g, (lds_u32_t*)l, 4, 0, 0);
}
// 16 B/lane: one instr moves 1024 B (256 floats); HW-verified width (m97).
__device__ __forceinline__ void gld16(const float* g, float* l){
  __builtin_amdgcn_global_load_lds((glb_u32_t*)g, (lds_u32_t*)l, 16, 0, 0);
}

// ---------------- kernel A: vmp + node-CG + wn mix -> mixed[256][72] -------
__global__ __launch_bounds__(256) void k_nodes(
                        const float* __restrict__ adj,
                        const float* __restrict__ v0,
                        const float* __restrict__ v1,
                        const float* __restrict__ v2,
                        const float* __restrict__ wn0,
                        const float* __restrict__ wn1,
                        const float* __restrict__ wn2,
                        float* __restrict__ mixed){
  __shared__ float part[4][72];
  int i = blockIdx.x;
  int tid = threadIdx.x, wv = tid >> 6, lane = tid & 63;
  {
    const float* vp1; int st1;
    if (lane < 8)       { vp1 = v0 + lane;      st1 = 8;  }
    else if (lane < 32) { vp1 = v1 + (lane-8);  st1 = 24; }
    else                { vp1 = v2 + (lane-32); st1 = 40; }
    const float* vp2 = v2 + 32 + lane;
    const float* arow = adj + i*NN;
    int j0 = wv*64;
    float a1a = 0.f, a1b = 0.f, a2a = 0.f, a2b = 0.f;
    #pragma unroll 8
    for (int j = j0; j < j0+64; j += 2){
      float av0 = arow[j], av1 = arow[j+1];
      a1a = fmaf(av0, vp1[j*st1], a1a);
      a1b = fmaf(av1, vp1[(j+1)*st1], a1b);
      if (lane < 8){
        a2a = fmaf(av0, vp2[j*40], a2a);
        a2b = fmaf(av1, vp2[(j+1)*40], a2b);
      }
    }
    part[wv][lane] = a1a + a1b;
    if (lane < 8) part[wv][64+lane] = a2a + a2b;
  }
  __syncthreads();
  if (wv) return;
  {
    float s = part[0][lane] + part[1][lane] + part[2][lane] + part[3][lane];
    float s2 = 0.f;
    if (lane < 8)
      s2 = part[0][64+lane] + part[1][64+lane] + part[2][64+lane] + part[3][64+lane];
    part[0][lane] = s;
    if (lane < 8) part[0][64+lane] = s2;
  }
  int c = lane >> 3, d = lane & 7;
  float mx[9], sv[9];
  #pragma unroll
  for (int j=0;j<9;j++){ mx[j] = part[0][j*8 + c]; sv[j] = part[0][j*8 + d]; }
  float r0[3], r1[3][6], r2[5][6];
  CGREL(mx, sv, r0, r1, r2)

  float a0[8], a1m[3][8], a2m[5][8];
  #pragma unroll
  for (int dp=0;dp<8;dp++){ a0[dp]=0.f;
    #pragma unroll
    for (int M=0;M<3;M++) a1m[M][dp]=0.f;
    #pragma unroll
    for (int M=0;M<5;M++) a2m[M][dp]=0.f;
  }
  #pragma unroll
  for (int k=0;k<3;k++){
    const float* row = wn0 + (k*64 + lane)*8;
    float4 u = *(const float4*)row;
    float4 v = *(const float4*)(row+4);
    float u8[8] = {u.x,u.y,u.z,u.w,v.x,v.y,v.z,v.w};
    #pragma unroll
    for (int dp=0;dp<8;dp++) a0[dp] = fmaf(r0[k], u8[dp], a0[dp]);
  }
  #pragma unroll
  for (int k=0;k<6;k++){
    const float* row = wn1 + (k*64 + lane)*8;
    float4 u = *(const float4*)row;
    float4 v = *(const float4*)(row+4);
    float u8[8] = {u.x,u.y,u.z,u.w,v.x,v.y,v.z,v.w};
    #pragma unroll
    for (int M=0;M<3;M++)
      #pragma unroll
      for (int dp=0;dp<8;dp++) a1m[M][dp] = fmaf(r1[M][k], u8[dp], a1m[M][dp]);
  }
  #pragma unroll
  for (int k=0;k<6;k++){
    const float* row = wn2 + (k*64 + lane)*8;
    float4 u = *(const float4*)row;
    float4 v = *(const float4*)(row+4);
    float u8[8] = {u.x,u.y,u.z,u.w,v.x,v.y,v.z,v.w};
    #pragma unroll
    for (int M=0;M<5;M++)
      #pragma unroll
      for (int dp=0;dp<8;dp++) a2m[M][dp] = fmaf(r2[M][k], u8[dp], a2m[M][dp]);
  }
  #pragma unroll
  for (int m=0;m<9;m++){
    #pragma unroll
    for (int dp=0;dp<8;dp++){
      float val = (m==0) ? a0[dp] : (m<4 ? a1m[m-1][dp] : a2m[m-4][dp]);
      val += __shfl_xor(val, 1);
      val += __shfl_xor(val, 2);
      val += __shfl_xor(val, 4);
      val += __shfl_xor(val, 8);
      val += __shfl_xor(val, 16);
      val += __shfl_xor(val, 32);
      if (lane == ((m*8+dp) & 63)) mixed[i*72 + m*8 + dp] = val;
    }
  }
}

// ---------------- kernel B: async-LDS pipelined pair kernel ----------------
// Per-wave LDS region (floats):
//   ring  [0, 2560)  : RING_D=2 slots x 1280
//     slot: wr0 @ [0..256) (192 real + pad), wr1 @ [256..768) (384 real + pad
//           at 640..768), wr2 @ [768..1280) (384 real + pad)
//   mixed [2560, 3328): 576 real + pad (8 rows x 72)
//   s0 [3328,3392) s1 [3392,3456) s2 [3456,3520): dup-slot scheme (R7)
#define WAVE_F 3520

// 5 size-16 instructions per pair; tail lanes use clamped dup addresses that
// land in LDS padding (never read). All 64 lanes always active.
__device__ __forceinline__ void prefetch_pair(
    int x, int y, int lane,
    const float* __restrict__ wr0, const float* __restrict__ wr1,
    const float* __restrict__ wr2, float* slotp){
  int pxy = x*NN + y;
  int l48 = (lane < 48) ? lane : 47;
  int l32 = (lane < 32) ? lane : 31;
  gld16(wr0 + (size_t)pxy*192 + l48*4,        slotp);          // floats 0..191 real
  gld16(wr1 + (size_t)pxy*384 + lane*4,       slotp + 256);    // wr1 0..255
  gld16(wr1 + (size_t)pxy*384 + 256 + l32*4,  slotp + 512);    // wr1 256..383 real
  gld16(wr2 + (size_t)pxy*384 + lane*4,       slotp + 768);    // wr2 0..255
  gld16(wr2 + (size_t)pxy*384 + 256 + l32*4,  slotp + 1024);   // wr2 256..383 real
}

// consume one pair: plain C++ LDS reads (ordered after the vmcnt asm by the
// "memory" clobber; aliasing with the prefetch intrinsic keeps issue order).
#define CONSUME(iIdx, slotIdx) { \
  const float* slotp = Lw + (slotIdx)*1280; \
  float w0v[3], w1v[6], w2v[6]; \
  _Pragma("unroll") for (int k=0;k<3;k++) w0v[k] = slotp[k*64 + lane]; \
  _Pragma("unroll") for (int k=0;k<6;k++) w1v[k] = slotp[256 + k*64 + lane]; \
  _Pragma("unroll") for (int k=0;k<6;k++) w2v[k] = slotp[768 + k*64 + lane]; \
  const float* mixp = Lw + 2560 + (iIdx)*72; \
  float mx[9], sv[9]; \
  _Pragma("unroll") for (int j=0;j<9;j++) mx[j] = mixp[j*8 + cgp]; \
  sv[0] = Lw[3328 + (iIdx)]; \
  _Pragma("unroll") for (int j=0;j<3;j++) sv[1+j] = Lw[3392 + (iIdx)*3 + j]; \
  _Pragma("unroll") for (int j=0;j<5;j++) sv[4+j] = Lw[3456 + (iIdx)*5 + j]; \
  float r0[3], r1[3][6], r2[5][6]; \
  CGREL(mx, sv, r0, r1, r2) \
  _Pragma("unroll") for (int k=0;k<3;k++) acc[0] = fmaf(r0[k], w0v[k], acc[0]); \
  _Pragma("unroll") for (int k=0;k<6;k++){ \
    acc[1] = fmaf(r1[0][k], w1v[k], acc[1]); \
    acc[2] = fmaf(r1[1][k], w1v[k], acc[2]); \
    acc[3] = fmaf(r1[2][k], w1v[k], acc[3]); \
    acc[4] = fmaf(r2[0][k], w2v[k], acc[4]); \
    acc[5] = fmaf(r2[1][k], w2v[k], acc[5]); \
    acc[6] = fmaf(r2[2][k], w2v[k], acc[6]); \
    acc[7] = fmaf(r2[3][k], w2v[k], acc[7]); \
    acc[8] = fmaf(r2[4][k], w2v[k], acc[8]); } }

#define WAITVM(n) { \
  asm volatile("s_waitcnt vmcnt(" #n ")" ::: "memory"); \
  __builtin_amdgcn_sched_barrier(0); }

__global__ __launch_bounds__(256) void k_pair(
    const float* __restrict__ mixed,
    const float* __restrict__ s0, const float* __restrict__ s1, const float* __restrict__ s2,
    const float* __restrict__ wr0, const float* __restrict__ wr1, const float* __restrict__ wr2,
    float* __restrict__ vsum){
  __shared__ float L[4][WAVE_F];
  int tid = threadIdx.x;
  int lane = tid & 63;
  int wv = tid >> 6;
  int w = blockIdx.x*4 + wv;
  int y = w & (NN-1);
  int xbase = (w >> 8) * XPW;
  int cgp = lane >> 3;
  float* Lw = &L[wv][0];

  // ---- prologue: mixed (3 instrs) + s (3 dup-slot) + RING_D pairs --------
  {
    const float* mb = mixed + xbase*72;
    int l16 = (lane < 16) ? lane : 15;
    gld16(mb + lane*4,       Lw + 2560);       // floats 0..255
    gld16(mb + 256 + lane*4, Lw + 2816);       // floats 256..511
    gld16(mb + 512 + l16*4,  Lw + 3072);       // floats 512..575 real
    gld4(s0 + (xbase + (lane & 7))*NN + y, Lw + 3328);
    { int e = lane < 24 ? lane : 23; int si = e/3, sj = e - si*3;
      gld4(s1 + ((size_t)((xbase+si)*NN + y))*3 + sj, Lw + 3392); }
    { int e = lane < 40 ? lane : 39; int si = e/5, sj = e - si*5;
      gld4(s2 + ((size_t)((xbase+si)*NN + y))*5 + sj, Lw + 3456); }
    #pragma unroll
    for (int p=0;p<RING_D;p++)
      prefetch_pair(xbase + p, y, lane, wr0, wr1, wr2, Lw + p*1280);
  }

  float acc[9];
  #pragma unroll
  for (int m=0;m<9;m++) acc[m]=0.f;

  // ---- main loop: 16 outstanding after prologue; steady vmcnt(5) ---------
  int slot = 0;
  for (int i=0;i<XPW-1;i++){
    WAITVM(5)
    CONSUME(i, slot);
    if (i < XPW-RING_D)
      prefetch_pair(xbase + i + RING_D, y, lane, wr0, wr1, wr2, Lw + slot*1280);
    slot ^= 1;
  }
  WAITVM(0)
  CONSUME(XPW-1, slot);

  // ---- reduce over cgp groups, atomic into vsum --------------------------
  #pragma unroll
  for (int m=0;m<9;m++){
    float v = acc[m];
    v += __shfl_xor(v, 8);
    v += __shfl_xor(v, 16);
    v += __shfl_xor(v, 32);
    acc[m] = v;
  }
  if (lane < 8){
    #pragma unroll
    for (int m=0;m<9;m++) atomicAdd(&vsum[y*72 + m*8 + lane], acc[m]);
  }
}

// ---------------- kernel C: part sums + normalize + write ------------------
__global__ void k_final(const float* __restrict__ vsum, float* __restrict__ out){
  __shared__ float ps[3];
  int t = threadIdx.x;   // 1024 threads; 18 elements each
  if (t < 3) ps[t] = 0.f;
  __syncthreads();
  float vals[18];
  float p0=0.f, p1=0.f, p2=0.f;
  #pragma unroll
  for (int k=0;k<18;k++){
    int idx = t*18 + k;
    float v = vsum[idx];
    vals[k] = v;
    int mall = (idx >> 3) % 9;
    if (mall == 0) p0 += v; else if (mall < 4) p1 += v; else p2 += v;
  }
  #pragma unroll
  for (int s=1; s<64; s<<=1){
    p0 += __shfl_xor(p0, s);
    p1 += __shfl_xor(p1, s);
    p2 += __shfl_xor(p2, s);
  }
  if ((t & 63) == 0){
    atomicAdd(&ps[0], p0);
    atomicAdd(&ps[1], p1);
    atomicAdd(&ps[2], p2);
  }
  __syncthreads();
  float q0 = ps[0], q1 = ps[1], q2 = ps[2];
  #pragma unroll
  for (int k=0;k<18;k++){
    int idx = t*18 + k;
    int mall = (idx >> 3) % 9;
    float den = (mall == 0) ? q0 : (mall < 4 ? q1 : q2);
    out[idx] = vals[k] / den;
  }
}

extern "C" void kernel_launch(void* const* d_in, const int* in_sizes, int n_in,
                              void* d_out, int out_size, void* d_ws, size_t ws_size,
                              hipStream_t stream) {
  const float* v0  = (const float*)d_in[0];
  const float* v1  = (const float*)d_in[1];
  const float* v2  = (const float*)d_in[2];
  const float* adj = (const float*)d_in[3];
  const float* s0  = (const float*)d_in[4];
  const float* s1  = (const float*)d_in[5];
  const float* s2  = (const float*)d_in[6];
  const float* wn0 = (const float*)d_in[7];
  const float* wn1 = (const float*)d_in[8];
  const float* wn2 = (const float*)d_in[9];
  const float* wr0 = (const float*)d_in[10];
  const float* wr1 = (const float*)d_in[11];
  const float* wr2 = (const float*)d_in[12];
  float* out = (float*)d_out;

  float* ws    = (float*)d_ws;
  float* mixed = ws;            // 18432
  float* vsum  = ws + 18432;    // 18432

  hipMemsetAsync(vsum, 0, 18432*sizeof(float), stream);
  k_nodes<<<NN, 256, 0, stream>>>(adj, v0, v1, v2, wn0, wn1, wn2, mixed);
  k_pair<<<NN*(NN/XPW)/4, 256, 0, stream>>>(mixed, s0, s1, s2, wr0, wr1, wr2, vsum);
  k_final<<<1, 1024, 0, stream>>>(vsum, out);
}

// Round 10
// 84.679 us; speedup vs baseline: 1.0911x; 1.0345x over previous
//
#include <hip/hip_runtime.h>

#define NN 256
#define XPW 4          // pairs (x values) per wave

// hard-coded CG constants (l<=2), float32
#define C13  0.5773502691896258f
#define C15  0.4472135954999579f
#define CC12 0.7071067811865476f
#define S35  0.7745966692414834f
#define S310 0.5477225575051661f
#define C110 0.3162277660168379f
#define S25  0.6324555320336759f
#define S23  0.8164965809277260f
#define C16  0.4082482904638630f
#define S27  0.5345224838248488f
#define S37  0.6546536707079771f
#define C114 0.2672612419124244f

#define CGREL(mx, sv, r0, r1, r2) \
    r0[0] = mx[0]*sv[0]; \
    r0[1] = C13*(mx[1]*sv[3] - mx[2]*sv[2] + mx[3]*sv[1]); \
    r0[2] = C15*(mx[4]*sv[8] - mx[5]*sv[7] + mx[6]*sv[6] - mx[7]*sv[5] + mx[8]*sv[4]); \
    r1[0][0] = mx[0]*sv[1]; r1[1][0] = mx[0]*sv[2]; r1[2][0] = mx[0]*sv[3]; \
    r1[0][1] = mx[1]*sv[0]; r1[1][1] = mx[2]*sv[0]; r1[2][1] = mx[3]*sv[0]; \
    r1[0][2] = CC12*(mx[2]*sv[1] - mx[1]*sv[2]); \
    r1[1][2] = CC12*(mx[3]*sv[1] - mx[1]*sv[3]); \
    r1[2][2] = CC12*(mx[3]*sv[2] - mx[2]*sv[3]); \
    r1[0][3] = S35*mx[3]*sv[4] - S310*mx[2]*sv[5] + C110*mx[1]*sv[6]; \
    r1[1][3] = S310*(mx[3]*sv[5] + mx[1]*sv[7]) - S25*mx[2]*sv[6]; \
    r1[2][3] = S35*mx[1]*sv[8] - S310*mx[2]*sv[7] + C110*mx[3]*sv[6]; \
    r1[0][4] = C110*mx[6]*sv[1] - S310*mx[5]*sv[2] + S35*mx[4]*sv[3]; \
    r1[1][4] = S310*(mx[7]*sv[1] + mx[5]*sv[3]) - S25*mx[6]*sv[2]; \
    r1[2][4] = S35*mx[8]*sv[1] - S310*mx[7]*sv[2] + C110*mx[6]*sv[3]; \
    r1[0][5] = C15*(mx[7]*sv[4] - mx[4]*sv[7]) + S310*(mx[5]*sv[6] - mx[6]*sv[5]); \
    r1[1][5] = S25*(mx[8]*sv[4] - mx[4]*sv[8]) + C110*(mx[5]*sv[7] - mx[7]*sv[5]); \
    r1[2][5] = C15*(mx[8]*sv[5] - mx[5]*sv[8]) + S310*(mx[6]*sv[7] - mx[7]*sv[6]); \
    r2[0][0]=mx[0]*sv[4]; r2[1][0]=mx[0]*sv[5]; r2[2][0]=mx[0]*sv[6]; r2[3][0]=mx[0]*sv[7]; r2[4][0]=mx[0]*sv[8]; \
    r2[0][1] = mx[1]*sv[1]; \
    r2[1][1] = CC12*(mx[2]*sv[1] + mx[1]*sv[2]); \
    r2[2][1] = C16*(mx[3]*sv[1] + mx[1]*sv[3]) + S23*mx[2]*sv[2]; \
    r2[3][1] = CC12*(mx[3]*sv[2] + mx[2]*sv[3]); \
    r2[4][1] = mx[3]*sv[3]; \
    r2[0][2] = S23*mx[2]*sv[4] - C13*mx[1]*sv[5]; \
    r2[1][2] = C13*mx[3]*sv[4] + C16*mx[2]*sv[5] - CC12*mx[1]*sv[6]; \
    r2[2][2] = CC12*(mx[3]*sv[5] - mx[1]*sv[7]); \
    r2[3][2] = CC12*mx[3]*sv[6] - C16*mx[2]*sv[7] - C13*mx[1]*sv[8]; \
    r2[4][2] = C13*mx[3]*sv[7] - S23*mx[2]*sv[8]; \
    r2[0][3]=mx[4]*sv[0]; r2[1][3]=mx[5]*sv[0]; r2[2][3]=mx[6]*sv[0]; r2[3][3]=mx[7]*sv[0]; r2[4][3]=mx[8]*sv[0]; \
    r2[0][4] = C13*mx[5]*sv[1] - S23*mx[4]*sv[2]; \
    r2[1][4] = CC12*mx[6]*sv[1] - C16*mx[5]*sv[2] - C13*mx[4]*sv[3]; \
    r2[2][4] = CC12*(mx[7]*sv[1] - mx[5]*sv[3]); \
    r2[3][4] = C13*mx[8]*sv[1] + C16*mx[7]*sv[2] - CC12*mx[6]*sv[3]; \
    r2[4][4] = S23*mx[8]*sv[2] - C13*mx[7]*sv[3]; \
    r2[0][5] = S27*(mx[4]*sv[6] + mx[6]*sv[4]) - S37*mx[5]*sv[5]; \
    r2[1][5] = S37*(mx[4]*sv[7] + mx[7]*sv[4]) - C114*(mx[5]*sv[6] + mx[6]*sv[5]); \
    r2[2][5] = S27*(mx[8]*sv[4] + mx[4]*sv[8] - mx[6]*sv[6]) + C114*(mx[7]*sv[5] + mx[5]*sv[7]); \
    r2[3][5] = S37*(mx[8]*sv[5] + mx[5]*sv[8]) - C114*(mx[7]*sv[6] + mx[6]*sv[7]); \
    r2[4][5] = S27*(mx[8]*sv[6] + mx[6]*sv[8]) - S37*mx[7]*sv[7];

// ---------------- kernel A: vmp + node-CG + wn mix -> mixed[256][72] -------
__global__ __launch_bounds__(256) void k_nodes(
                        const float* __restrict__ adj,
                        const float* __restrict__ v0,
                        const float* __restrict__ v1,
                        const float* __restrict__ v2,
                        const float* __restrict__ wn0,
                        const float* __restrict__ wn1,
                        const float* __restrict__ wn2,
                        float* __restrict__ mixed){
  __shared__ float part[4][72];
  int i = blockIdx.x;
  int tid = threadIdx.x, wv = tid >> 6, lane = tid & 63;
  {
    const float* vp1; int st1;
    if (lane < 8)       { vp1 = v0 + lane;      st1 = 8;  }
    else if (lane < 32) { vp1 = v1 + (lane-8);  st1 = 24; }
    else                { vp1 = v2 + (lane-32); st1 = 40; }
    const float* vp2 = v2 + 32 + lane;
    const float* arow = adj + i*NN;
    int j0 = wv*64;
    float a1a = 0.f, a1b = 0.f, a2a = 0.f, a2b = 0.f;
    #pragma unroll 8
    for (int j = j0; j < j0+64; j += 2){
      float av0 = arow[j], av1 = arow[j+1];
      a1a = fmaf(av0, vp1[j*st1], a1a);
      a1b = fmaf(av1, vp1[(j+1)*st1], a1b);
      if (lane < 8){
        a2a = fmaf(av0, vp2[j*40], a2a);
        a2b = fmaf(av1, vp2[(j+1)*40], a2b);
      }
    }
    part[wv][lane] = a1a + a1b;
    if (lane < 8) part[wv][64+lane] = a2a + a2b;
  }
  __syncthreads();
  if (wv) return;
  {
    float s = part[0][lane] + part[1][lane] + part[2][lane] + part[3][lane];
    float s2 = 0.f;
    if (lane < 8)
      s2 = part[0][64+lane] + part[1][64+lane] + part[2][64+lane] + part[3][64+lane];
    part[0][lane] = s;
    if (lane < 8) part[0][64+lane] = s2;
  }
  int c = lane >> 3, d = lane & 7;
  float mx[9], sv[9];
  #pragma unroll
  for (int j=0;j<9;j++){ mx[j] = part[0][j*8 + c]; sv[j] = part[0][j*8 + d]; }
  float r0[3], r1[3][6], r2[5][6];
  CGREL(mx, sv, r0, r1, r2)

  float a0[8], a1m[3][8], a2m[5][8];
  #pragma unroll
  for (int dp=0;dp<8;dp++){ a0[dp]=0.f;
    #pragma unroll
    for (int M=0;M<3;M++) a1m[M][dp]=0.f;
    #pragma unroll
    for (int M=0;M<5;M++) a2m[M][dp]=0.f;
  }
  #pragma unroll
  for (int k=0;k<3;k++){
    const float* row = wn0 + (k*64 + lane)*8;
    float4 u = *(const float4*)row;
    float4 v = *(const float4*)(row+4);
    float u8[8] = {u.x,u.y,u.z,u.w,v.x,v.y,v.z,v.w};
    #pragma unroll
    for (int dp=0;dp<8;dp++) a0[dp] = fmaf(r0[k], u8[dp], a0[dp]);
  }
  #pragma unroll
  for (int k=0;k<6;k++){
    const float* row = wn1 + (k*64 + lane)*8;
    float4 u = *(const float4*)row;
    float4 v = *(const float4*)(row+4);
    float u8[8] = {u.x,u.y,u.z,u.w,v.x,v.y,v.z,v.w};
    #pragma unroll
    for (int M=0;M<3;M++)
      #pragma unroll
      for (int dp=0;dp<8;dp++) a1m[M][dp] = fmaf(r1[M][k], u8[dp], a1m[M][dp]);
  }
  #pragma unroll
  for (int k=0;k<6;k++){
    const float* row = wn2 + (k*64 + lane)*8;
    float4 u = *(const float4*)row;
    float4 v = *(const float4*)(row+4);
    float u8[8] = {u.x,u.y,u.z,u.w,v.x,v.y,v.z,v.w};
    #pragma unroll
    for (int M=0;M<5;M++)
      #pragma unroll
      for (int dp=0;dp<8;dp++) a2m[M][dp] = fmaf(r2[M][k], u8[dp], a2m[M][dp]);
  }
  #pragma unroll
  for (int m=0;m<9;m++){
    #pragma unroll
    for (int dp=0;dp<8;dp++){
      float val = (m==0) ? a0[dp] : (m<4 ? a1m[m-1][dp] : a2m[m-4][dp]);
      val += __shfl_xor(val, 1);
      val += __shfl_xor(val, 2);
      val += __shfl_xor(val, 4);
      val += __shfl_xor(val, 8);
      val += __shfl_xor(val, 16);
      val += __shfl_xor(val, 32);
      if (lane == ((m*8+dp) & 63)) mixed[i*72 + m*8 + dp] = val;
    }
  }
}

// ---------------- kernel B: pairwise CG + wr mix, max-occupancy ------------
// 4096 blocks x 4 waves = 16384 waves (64/CU demanded -> residency-capped).
// Register consume, compiler-scheduled loads; TLP (8 waves/SIMD) hides latency.
// 4 waves share y -> LDS cross-wave reduce -> 1 atomic set per block.
__global__ __launch_bounds__(256) void k_pair(
    const float* __restrict__ mixed,
    const float* __restrict__ s0, const float* __restrict__ s1, const float* __restrict__ s2,
    const float* __restrict__ wr0, const float* __restrict__ wr1, const float* __restrict__ wr2,
    float* __restrict__ vsum){
  __shared__ float red[4][72];
  int tid = threadIdx.x;
  int wv = tid >> 6, lane = tid & 63;
  int y = blockIdx.x & (NN-1);
  int xsel = blockIdx.x >> 8;              // 0..15
  int xbase = (xsel*4 + wv) * XPW;
  int cgp = lane >> 3;

  float acc[9];
  #pragma unroll
  for (int m=0;m<9;m++) acc[m]=0.f;

  #pragma unroll
  for (int i=0;i<XPW;i++){
    int x = xbase + i;
    int pxy = x*NN + y;
    const float* p0 = wr0 + (size_t)pxy*192 + lane;
    const float* p1 = wr1 + (size_t)pxy*384 + lane;
    const float* p2 = wr2 + (size_t)pxy*384 + lane;
    float w0v[3], w1v[6], w2v[6];
    #pragma unroll
    for (int k=0;k<3;k++) w0v[k] = p0[k*64];
    #pragma unroll
    for (int k=0;k<6;k++) w1v[k] = p1[k*64];
    #pragma unroll
    for (int k=0;k<6;k++) w2v[k] = p2[k*64];

    float mx[9], sv[9];
    {
      const float* mb = mixed + x*72 + cgp;
      #pragma unroll
      for (int j=0;j<9;j++) mx[j] = mb[j*8];
      sv[0] = s0[pxy];
      #pragma unroll
      for (int j=0;j<3;j++) sv[1+j] = s1[(size_t)pxy*3+j];
      #pragma unroll
      for (int j=0;j<5;j++) sv[4+j] = s2[(size_t)pxy*5+j];
    }

    float r0[3], r1[3][6], r2[5][6];
    CGREL(mx, sv, r0, r1, r2)

    #pragma unroll
    for (int k=0;k<3;k++) acc[0] = fmaf(r0[k], w0v[k], acc[0]);
    #pragma unroll
    for (int k=0;k<6;k++){
      acc[1] = fmaf(r1[0][k], w1v[k], acc[1]);
      acc[2] = fmaf(r1[1][k], w1v[k], acc[2]);
      acc[3] = fmaf(r1[2][k], w1v[k], acc[3]);
      acc[4] = fmaf(r2[0][k], w2v[k], acc[4]);
      acc[5] = fmaf(r2[1][k], w2v[k], acc[5]);
      acc[6] = fmaf(r2[2][k], w2v[k], acc[6]);
      acc[7] = fmaf(r2[3][k], w2v[k], acc[7]);
      acc[8] = fmaf(r2[4][k], w2v[k], acc[8]);
    }
  }

  // reduce over cgp groups (lane bits 3..5)
  #pragma unroll
  for (int m=0;m<9;m++){
    float v = acc[m];
    v += __shfl_xor(v, 8);
    v += __shfl_xor(v, 16);
    v += __shfl_xor(v, 32);
    acc[m] = v;
  }
  if (lane < 8){
    #pragma unroll
    for (int m=0;m<9;m++) red[wv][m*8+lane] = acc[m];
  }
  __syncthreads();
  if (tid < 72){
    float v = red[0][tid] + red[1][tid] + red[2][tid] + red[3][tid];
    atomicAdd(&vsum[y*72 + tid], v);
  }
}

// ---------------- kernel C: part sums + normalize + write ------------------
__global__ void k_final(const float* __restrict__ vsum, float* __restrict__ out){
  __shared__ float ps[3];
  int t = threadIdx.x;   // 1024 threads; 18 elements each
  if (t < 3) ps[t] = 0.f;
  __syncthreads();
  float vals[18];
  float p0=0.f, p1=0.f, p2=0.f;
  #pragma unroll
  for (int k=0;k<18;k++){
    int idx = t*18 + k;
    float v = vsum[idx];
    vals[k] = v;
    int mall = (idx >> 3) % 9;
    if (mall == 0) p0 += v; else if (mall < 4) p1 += v; else p2 += v;
  }
  #pragma unroll
  for (int s=1; s<64; s<<=1){
    p0 += __shfl_xor(p0, s);
    p1 += __shfl_xor(p1, s);
    p2 += __shfl_xor(p2, s);
  }
  if ((t & 63) == 0){
    atomicAdd(&ps[0], p0);
    atomicAdd(&ps[1], p1);
    atomicAdd(&ps[2], p2);
  }
  __syncthreads();
  float q0 = ps[0], q1 = ps[1], q2 = ps[2];
  #pragma unroll
  for (int k=0;k<18;k++){
    int idx = t*18 + k;
    int mall = (idx >> 3) % 9;
    float den = (mall == 0) ? q0 : (mall < 4 ? q1 : q2);
    out[idx] = vals[k] / den;
  }
}

extern "C" void kernel_launch(void* const* d_in, const int* in_sizes, int n_in,
                              void* d_out, int out_size, void* d_ws, size_t ws_size,
                              hipStream_t stream) {
  const float* v0  = (const float*)d_in[0];
  const float* v1  = (const float*)d_in[1];
  const float* v2  = (const float*)d_in[2];
  const float* adj = (const float*)d_in[3];
  const float* s0  = (const float*)d_in[4];
  const float* s1  = (const float*)d_in[5];
  const float* s2  = (const float*)d_in[6];
  const float* wn0 = (const float*)d_in[7];
  const float* wn1 = (const float*)d_in[8];
  const float* wn2 = (const float*)d_in[9];
  const float* wr0 = (const float*)d_in[10];
  const float* wr1 = (const float*)d_in[11];
  const float* wr2 = (const float*)d_in[12];
  float* out = (float*)d_out;

  float* ws    = (float*)d_ws;
  float* mixed = ws;            // 18432
  float* vsum  = ws + 18432;    // 18432

  hipMemsetAsync(vsum, 0, 18432*sizeof(float), stream);
  k_nodes<<<NN, 256, 0, stream>>>(adj, v0, v1, v2, wn0, wn1, wn2, mixed);
  k_pair<<<NN*16, 256, 0, stream>>>(mixed, s0, s1, s2, wr0, wr1, wr2, vsum);
  k_final<<<1, 1024, 0, stream>>>(vsum, out);
}

// Round 11
// 83.681 us; speedup vs baseline: 1.1041x; 1.0119x over previous
//
#include <hip/hip_runtime.h>

#define NN 256
#define XPW 4          // pairs (x values) per wave

// hard-coded CG constants (l<=2), float32
#define C13  0.5773502691896258f
#define C15  0.4472135954999579f
#define CC12 0.7071067811865476f
#define S35  0.7745966692414834f
#define S310 0.5477225575051661f
#define C110 0.3162277660168379f
#define S25  0.6324555320336759f
#define S23  0.8164965809277260f
#define C16  0.4082482904638630f
#define S27  0.5345224838248488f
#define S37  0.6546536707079771f
#define C114 0.2672612419124244f

#define CGREL(mx, sv, r0, r1, r2) \
    r0[0] = mx[0]*sv[0]; \
    r0[1] = C13*(mx[1]*sv[3] - mx[2]*sv[2] + mx[3]*sv[1]); \
    r0[2] = C15*(mx[4]*sv[8] - mx[5]*sv[7] + mx[6]*sv[6] - mx[7]*sv[5] + mx[8]*sv[4]); \
    r1[0][0] = mx[0]*sv[1]; r1[1][0] = mx[0]*sv[2]; r1[2][0] = mx[0]*sv[3]; \
    r1[0][1] = mx[1]*sv[0]; r1[1][1] = mx[2]*sv[0]; r1[2][1] = mx[3]*sv[0]; \
    r1[0][2] = CC12*(mx[2]*sv[1] - mx[1]*sv[2]); \
    r1[1][2] = CC12*(mx[3]*sv[1] - mx[1]*sv[3]); \
    r1[2][2] = CC12*(mx[3]*sv[2] - mx[2]*sv[3]); \
    r1[0][3] = S35*mx[3]*sv[4] - S310*mx[2]*sv[5] + C110*mx[1]*sv[6]; \
    r1[1][3] = S310*(mx[3]*sv[5] + mx[1]*sv[7]) - S25*mx[2]*sv[6]; \
    r1[2][3] = S35*mx[1]*sv[8] - S310*mx[2]*sv[7] + C110*mx[3]*sv[6]; \
    r1[0][4] = C110*mx[6]*sv[1] - S310*mx[5]*sv[2] + S35*mx[4]*sv[3]; \
    r1[1][4] = S310*(mx[7]*sv[1] + mx[5]*sv[3]) - S25*mx[6]*sv[2]; \
    r1[2][4] = S35*mx[8]*sv[1] - S310*mx[7]*sv[2] + C110*mx[6]*sv[3]; \
    r1[0][5] = C15*(mx[7]*sv[4] - mx[4]*sv[7]) + S310*(mx[5]*sv[6] - mx[6]*sv[5]); \
    r1[1][5] = S25*(mx[8]*sv[4] - mx[4]*sv[8]) + C110*(mx[5]*sv[7] - mx[7]*sv[5]); \
    r1[2][5] = C15*(mx[8]*sv[5] - mx[5]*sv[8]) + S310*(mx[6]*sv[7] - mx[7]*sv[6]); \
    r2[0][0]=mx[0]*sv[4]; r2[1][0]=mx[0]*sv[5]; r2[2][0]=mx[0]*sv[6]; r2[3][0]=mx[0]*sv[7]; r2[4][0]=mx[0]*sv[8]; \
    r2[0][1] = mx[1]*sv[1]; \
    r2[1][1] = CC12*(mx[2]*sv[1] + mx[1]*sv[2]); \
    r2[2][1] = C16*(mx[3]*sv[1] + mx[1]*sv[3]) + S23*mx[2]*sv[2]; \
    r2[3][1] = CC12*(mx[3]*sv[2] + mx[2]*sv[3]); \
    r2[4][1] = mx[3]*sv[3]; \
    r2[0][2] = S23*mx[2]*sv[4] - C13*mx[1]*sv[5]; \
    r2[1][2] = C13*mx[3]*sv[4] + C16*mx[2]*sv[5] - CC12*mx[1]*sv[6]; \
    r2[2][2] = CC12*(mx[3]*sv[5] - mx[1]*sv[7]); \
    r2[3][2] = CC12*mx[3]*sv[6] - C16*mx[2]*sv[7] - C13*mx[1]*sv[8]; \
    r2[4][2] = C13*mx[3]*sv[7] - S23*mx[2]*sv[8]; \
    r2[0][3]=mx[4]*sv[0]; r2[1][3]=mx[5]*sv[0]; r2[2][3]=mx[6]*sv[0]; r2[3][3]=mx[7]*sv[0]; r2[4][3]=mx[8]*sv[0]; \
    r2[0][4] = C13*mx[5]*sv[1] - S23*mx[4]*sv[2]; \
    r2[1][4] = CC12*mx[6]*sv[1] - C16*mx[5]*sv[2] - C13*mx[4]*sv[3]; \
    r2[2][4] = CC12*(mx[7]*sv[1] - mx[5]*sv[3]); \
    r2[3][4] = C13*mx[8]*sv[1] + C16*mx[7]*sv[2] - CC12*mx[6]*sv[3]; \
    r2[4][4] = S23*mx[8]*sv[2] - C13*mx[7]*sv[3]; \
    r2[0][5] = S27*(mx[4]*sv[6] + mx[6]*sv[4]) - S37*mx[5]*sv[5]; \
    r2[1][5] = S37*(mx[4]*sv[7] + mx[7]*sv[4]) - C114*(mx[5]*sv[6] + mx[6]*sv[5]); \
    r2[2][5] = S27*(mx[8]*sv[4] + mx[4]*sv[8] - mx[6]*sv[6]) + C114*(mx[7]*sv[5] + mx[5]*sv[7]); \
    r2[3][5] = S37*(mx[8]*sv[5] + mx[5]*sv[8]) - C114*(mx[7]*sv[6] + mx[6]*sv[7]); \
    r2[4][5] = S27*(mx[8]*sv[6] + mx[6]*sv[8]) - S37*mx[7]*sv[7];

// ---------------- kernel A: vmp + node-CG + wn mix -> mixed[256][72] -------
__global__ __launch_bounds__(256) void k_nodes(
                        const float* __restrict__ adj,
                        const float* __restrict__ v0,
                        const float* __restrict__ v1,
                        const float* __restrict__ v2,
                        const float* __restrict__ wn0,
                        const float* __restrict__ wn1,
                        const float* __restrict__ wn2,
                        float* __restrict__ mixed){
  __shared__ float part[4][72];
  int i = blockIdx.x;
  int tid = threadIdx.x, wv = tid >> 6, lane = tid & 63;
  {
    const float* vp1; int st1;
    if (lane < 8)       { vp1 = v0 + lane;      st1 = 8;  }
    else if (lane < 32) { vp1 = v1 + (lane-8);  st1 = 24; }
    else                { vp1 = v2 + (lane-32); st1 = 40; }
    const float* vp2 = v2 + 32 + lane;
    const float* arow = adj + i*NN;
    int j0 = wv*64;
    float a1a = 0.f, a1b = 0.f, a2a = 0.f, a2b = 0.f;
    #pragma unroll 8
    for (int j = j0; j < j0+64; j += 2){
      float av0 = arow[j], av1 = arow[j+1];
      a1a = fmaf(av0, vp1[j*st1], a1a);
      a1b = fmaf(av1, vp1[(j+1)*st1], a1b);
      if (lane < 8){
        a2a = fmaf(av0, vp2[j*40], a2a);
        a2b = fmaf(av1, vp2[(j+1)*40], a2b);
      }
    }
    part[wv][lane] = a1a + a1b;
    if (lane < 8) part[wv][64+lane] = a2a + a2b;
  }
  __syncthreads();
  if (wv) return;
  {
    float s = part[0][lane] + part[1][lane] + part[2][lane] + part[3][lane];
    float s2 = 0.f;
    if (lane < 8)
      s2 = part[0][64+lane] + part[1][64+lane] + part[2][64+lane] + part[3][64+lane];
    part[0][lane] = s;
    if (lane < 8) part[0][64+lane] = s2;
  }
  int c = lane >> 3, d = lane & 7;
  float mx[9], sv[9];
  #pragma unroll
  for (int j=0;j<9;j++){ mx[j] = part[0][j*8 + c]; sv[j] = part[0][j*8 + d]; }
  float r0[3], r1[3][6], r2[5][6];
  CGREL(mx, sv, r0, r1, r2)

  float a0[8], a1m[3][8], a2m[5][8];
  #pragma unroll
  for (int dp=0;dp<8;dp++){ a0[dp]=0.f;
    #pragma unroll
    for (int M=0;M<3;M++) a1m[M][dp]=0.f;
    #pragma unroll
    for (int M=0;M<5;M++) a2m[M][dp]=0.f;
  }
  #pragma unroll
  for (int k=0;k<3;k++){
    const float* row = wn0 + (k*64 + lane)*8;
    float4 u = *(const float4*)row;
    float4 v = *(const float4*)(row+4);
    float u8[8] = {u.x,u.y,u.z,u.w,v.x,v.y,v.z,v.w};
    #pragma unroll
    for (int dp=0;dp<8;dp++) a0[dp] = fmaf(r0[k], u8[dp], a0[dp]);
  }
  #pragma unroll
  for (int k=0;k<6;k++){
    const float* row = wn1 + (k*64 + lane)*8;
    float4 u = *(const float4*)row;
    float4 v = *(const float4*)(row+4);
    float u8[8] = {u.x,u.y,u.z,u.w,v.x,v.y,v.z,v.w};
    #pragma unroll
    for (int M=0;M<3;M++)
      #pragma unroll
      for (int dp=0;dp<8;dp++) a1m[M][dp] = fmaf(r1[M][k], u8[dp], a1m[M][dp]);
  }
  #pragma unroll
  for (int k=0;k<6;k++){
    const float* row = wn2 + (k*64 + lane)*8;
    float4 u = *(const float4*)row;
    float4 v = *(const float4*)(row+4);
    float u8[8] = {u.x,u.y,u.z,u.w,v.x,v.y,v.z,v.w};
    #pragma unroll
    for (int M=0;M<5;M++)
      #pragma unroll
      for (int dp=0;dp<8;dp++) a2m[M][dp] = fmaf(r2[M][k], u8[dp], a2m[M][dp]);
  }
  #pragma unroll
  for (int m=0;m<9;m++){
    #pragma unroll
    for (int dp=0;dp<8;dp++){
      float val = (m==0) ? a0[dp] : (m<4 ? a1m[m-1][dp] : a2m[m-4][dp]);
      val += __shfl_xor(val, 1);
      val += __shfl_xor(val, 2);
      val += __shfl_xor(val, 4);
      val += __shfl_xor(val, 8);
      val += __shfl_xor(val, 16);
      val += __shfl_xor(val, 32);
      if (lane == ((m*8+dp) & 63)) mixed[i*72 + m*8 + dp] = val;
    }
  }
}

// ---------------- kernel B: pairwise CG + wr mix, nt wr stream -------------
// 4096 blocks x 4 waves. wr loads are NON-TEMPORAL: the 252 MB single-use
// stream bypasses cache allocation -> no L3 thrash, HBM streaming rate.
__global__ __launch_bounds__(256) void k_pair(
    const float* __restrict__ mixed,
    const float* __restrict__ s0, const float* __restrict__ s1, const float* __restrict__ s2,
    const float* __restrict__ wr0, const float* __restrict__ wr1, const float* __restrict__ wr2,
    float* __restrict__ vsum){
  __shared__ float red[4][72];
  int tid = threadIdx.x;
  int wv = tid >> 6, lane = tid & 63;
  int y = blockIdx.x & (NN-1);
  int xsel = blockIdx.x >> 8;              // 0..15
  int xbase = (xsel*4 + wv) * XPW;
  int cgp = lane >> 3;

  float acc[9];
  #pragma unroll
  for (int m=0;m<9;m++) acc[m]=0.f;

  #pragma unroll
  for (int i=0;i<XPW;i++){
    int x = xbase + i;
    int pxy = x*NN + y;
    const float* p0 = wr0 + (size_t)pxy*192 + lane;
    const float* p1 = wr1 + (size_t)pxy*384 + lane;
    const float* p2 = wr2 + (size_t)pxy*384 + lane;
    float w0v[3], w1v[6], w2v[6];
    #pragma unroll
    for (int k=0;k<3;k++) w0v[k] = __builtin_nontemporal_load(p0 + k*64);
    #pragma unroll
    for (int k=0;k<6;k++) w1v[k] = __builtin_nontemporal_load(p1 + k*64);
    #pragma unroll
    for (int k=0;k<6;k++) w2v[k] = __builtin_nontemporal_load(p2 + k*64);

    float mx[9], sv[9];
    {
      const float* mb = mixed + x*72 + cgp;
      #pragma unroll
      for (int j=0;j<9;j++) mx[j] = mb[j*8];
      sv[0] = s0[pxy];
      #pragma unroll
      for (int j=0;j<3;j++) sv[1+j] = s1[(size_t)pxy*3+j];
      #pragma unroll
      for (int j=0;j<5;j++) sv[4+j] = s2[(size_t)pxy*5+j];
    }

    float r0[3], r1[3][6], r2[5][6];
    CGREL(mx, sv, r0, r1, r2)

    #pragma unroll
    for (int k=0;k<3;k++) acc[0] = fmaf(r0[k], w0v[k], acc[0]);
    #pragma unroll
    for (int k=0;k<6;k++){
      acc[1] = fmaf(r1[0][k], w1v[k], acc[1]);
      acc[2] = fmaf(r1[1][k], w1v[k], acc[2]);
      acc[3] = fmaf(r1[2][k], w1v[k], acc[3]);
      acc[4] = fmaf(r2[0][k], w2v[k], acc[4]);
      acc[5] = fmaf(r2[1][k], w2v[k], acc[5]);
      acc[6] = fmaf(r2[2][k], w2v[k], acc[6]);
      acc[7] = fmaf(r2[3][k], w2v[k], acc[7]);
      acc[8] = fmaf(r2[4][k], w2v[k], acc[8]);
    }
  }

  // reduce over cgp groups (lane bits 3..5)
  #pragma unroll
  for (int m=0;m<9;m++){
    float v = acc[m];
    v += __shfl_xor(v, 8);
    v += __shfl_xor(v, 16);
    v += __shfl_xor(v, 32);
    acc[m] = v;
  }
  if (lane < 8){
    #pragma unroll
    for (int m=0;m<9;m++) red[wv][m*8+lane] = acc[m];
  }
  __syncthreads();
  if (tid < 72){
    float v = red[0][tid] + red[1][tid] + red[2][tid] + red[3][tid];
    atomicAdd(&vsum[y*72 + tid], v);
  }
}

// ---------------- kernel C: part sums + normalize + write ------------------
__global__ void k_final(const float* __restrict__ vsum, float* __restrict__ out){
  __shared__ float ps[3];
  int t = threadIdx.x;   // 1024 threads; 18 elements each
  if (t < 3) ps[t] = 0.f;
  __syncthreads();
  float vals[18];
  float p0=0.f, p1=0.f, p2=0.f;
  #pragma unroll
  for (int k=0;k<18;k++){
    int idx = t*18 + k;
    float v = vsum[idx];
    vals[k] = v;
    int mall = (idx >> 3) % 9;
    if (mall == 0) p0 += v; else if (mall < 4) p1 += v; else p2 += v;
  }
  #pragma unroll
  for (int s=1; s<64; s<<=1){
    p0 += __shfl_xor(p0, s);
    p1 += __shfl_xor(p1, s);
    p2 += __shfl_xor(p2, s);
  }
  if ((t & 63) == 0){
    atomicAdd(&ps[0], p0);
    atomicAdd(&ps[1], p1);
    atomicAdd(&ps[2], p2);
  }
  __syncthreads();
  float q0 = ps[0], q1 = ps[1], q2 = ps[2];
  #pragma unroll
  for (int k=0;k<18;k++){
    int idx = t*18 + k;
    int mall = (idx >> 3) % 9;
    float den = (mall == 0) ? q0 : (mall < 4 ? q1 : q2);
    out[idx] = vals[k] / den;
  }
}

extern "C" void kernel_launch(void* const* d_in, const int* in_sizes, int n_in,
                              void* d_out, int out_size, void* d_ws, size_t ws_size,
                              hipStream_t stream) {
  const float* v0  = (const float*)d_in[0];
  const float* v1  = (const float*)d_in[1];
  const float* v2  = (const float*)d_in[2];
  const float* adj = (const float*)d_in[3];
  const float* s0  = (const float*)d_in[4];
  const float* s1  = (const float*)d_in[5];
  const float* s2  = (const float*)d_in[6];
  const float* wn0 = (const float*)d_in[7];
  const float* wn1 = (const float*)d_in[8];
  const float* wn2 = (const float*)d_in[9];
  const float* wr0 = (const float*)d_in[10];
  const float* wr1 = (const float*)d_in[11];
  const float* wr2 = (const float*)d_in[12];
  float* out = (float*)d_out;

  float* ws    = (float*)d_ws;
  float* mixed = ws;            // 18432
  float* vsum  = ws + 18432;    // 18432

  hipMemsetAsync(vsum, 0, 18432*sizeof(float), stream);
  k_nodes<<<NN, 256, 0, stream>>>(adj, v0, v1, v2, wn0, wn1, wn2, mixed);
  k_pair<<<NN*16, 256, 0, stream>>>(mixed, s0, s1, s2, wr0, wr1, wr2, vsum);
  k_final<<<1, 1024, 0, stream>>>(vsum, out);
}

// Round 12
// 80.207 us; speedup vs baseline: 1.1520x; 1.0433x over previous
//
#include <hip/hip_runtime.h>

#define NN 256
#define XPW 8          // pairs (x values) per wave
#define NXS (NN/(4*XPW))   // 8 xsel groups

// hard-coded CG constants (l<=2), float32
#define C13  0.5773502691896258f
#define C15  0.4472135954999579f
#define CC12 0.7071067811865476f
#define S35  0.7745966692414834f
#define S310 0.5477225575051661f
#define C110 0.3162277660168379f
#define S25  0.6324555320336759f
#define S23  0.8164965809277260f
#define C16  0.4082482904638630f
#define S27  0.5345224838248488f
#define S37  0.6546536707079771f
#define C114 0.2672612419124244f

#define CGREL(mx, sv, r0, r1, r2) \
    r0[0] = mx[0]*sv[0]; \
    r0[1] = C13*(mx[1]*sv[3] - mx[2]*sv[2] + mx[3]*sv[1]); \
    r0[2] = C15*(mx[4]*sv[8] - mx[5]*sv[7] + mx[6]*sv[6] - mx[7]*sv[5] + mx[8]*sv[4]); \
    r1[0][0] = mx[0]*sv[1]; r1[1][0] = mx[0]*sv[2]; r1[2][0] = mx[0]*sv[3]; \
    r1[0][1] = mx[1]*sv[0]; r1[1][1] = mx[2]*sv[0]; r1[2][1] = mx[3]*sv[0]; \
    r1[0][2] = CC12*(mx[2]*sv[1] - mx[1]*sv[2]); \
    r1[1][2] = CC12*(mx[3]*sv[1] - mx[1]*sv[3]); \
    r1[2][2] = CC12*(mx[3]*sv[2] - mx[2]*sv[3]); \
    r1[0][3] = S35*mx[3]*sv[4] - S310*mx[2]*sv[5] + C110*mx[1]*sv[6]; \
    r1[1][3] = S310*(mx[3]*sv[5] + mx[1]*sv[7]) - S25*mx[2]*sv[6]; \
    r1[2][3] = S35*mx[1]*sv[8] - S310*mx[2]*sv[7] + C110*mx[3]*sv[6]; \
    r1[0][4] = C110*mx[6]*sv[1] - S310*mx[5]*sv[2] + S35*mx[4]*sv[3]; \
    r1[1][4] = S310*(mx[7]*sv[1] + mx[5]*sv[3]) - S25*mx[6]*sv[2]; \
    r1[2][4] = S35*mx[8]*sv[1] - S310*mx[7]*sv[2] + C110*mx[6]*sv[3]; \
    r1[0][5] = C15*(mx[7]*sv[4] - mx[4]*sv[7]) + S310*(mx[5]*sv[6] - mx[6]*sv[5]); \
    r1[1][5] = S25*(mx[8]*sv[4] - mx[4]*sv[8]) + C110*(mx[5]*sv[7] - mx[7]*sv[5]); \
    r1[2][5] = C15*(mx[8]*sv[5] - mx[5]*sv[8]) + S310*(mx[6]*sv[7] - mx[7]*sv[6]); \
    r2[0][0]=mx[0]*sv[4]; r2[1][0]=mx[0]*sv[5]; r2[2][0]=mx[0]*sv[6]; r2[3][0]=mx[0]*sv[7]; r2[4][0]=mx[0]*sv[8]; \
    r2[0][1] = mx[1]*sv[1]; \
    r2[1][1] = CC12*(mx[2]*sv[1] + mx[1]*sv[2]); \
    r2[2][1] = C16*(mx[3]*sv[1] + mx[1]*sv[3]) + S23*mx[2]*sv[2]; \
    r2[3][1] = CC12*(mx[3]*sv[2] + mx[2]*sv[3]); \
    r2[4][1] = mx[3]*sv[3]; \
    r2[0][2] = S23*mx[2]*sv[4] - C13*mx[1]*sv[5]; \
    r2[1][2] = C13*mx[3]*sv[4] + C16*mx[2]*sv[5] - CC12*mx[1]*sv[6]; \
    r2[2][2] = CC12*(mx[3]*sv[5] - mx[1]*sv[7]); \
    r2[3][2] = CC12*mx[3]*sv[6] - C16*mx[2]*sv[7] - C13*mx[1]*sv[8]; \
    r2[4][2] = C13*mx[3]*sv[7] - S23*mx[2]*sv[8]; \
    r2[0][3]=mx[4]*sv[0]; r2[1][3]=mx[5]*sv[0]; r2[2][3]=mx[6]*sv[0]; r2[3][3]=mx[7]*sv[0]; r2[4][3]=mx[8]*sv[0]; \
    r2[0][4] = C13*mx[5]*sv[1] - S23*mx[4]*sv[2]; \
    r2[1][4] = CC12*mx[6]*sv[1] - C16*mx[5]*sv[2] - C13*mx[4]*sv[3]; \
    r2[2][4] = CC12*(mx[7]*sv[1] - mx[5]*sv[3]); \
    r2[3][4] = C13*mx[8]*sv[1] + C16*mx[7]*sv[2] - CC12*mx[6]*sv[3]; \
    r2[4][4] = S23*mx[8]*sv[2] - C13*mx[7]*sv[3]; \
    r2[0][5] = S27*(mx[4]*sv[6] + mx[6]*sv[4]) - S37*mx[5]*sv[5]; \
    r2[1][5] = S37*(mx[4]*sv[7] + mx[7]*sv[4]) - C114*(mx[5]*sv[6] + mx[6]*sv[5]); \
    r2[2][5] = S27*(mx[8]*sv[4] + mx[4]*sv[8] - mx[6]*sv[6]) + C114*(mx[7]*sv[5] + mx[5]*sv[7]); \
    r2[3][5] = S37*(mx[8]*sv[5] + mx[5]*sv[8]) - C114*(mx[7]*sv[6] + mx[6]*sv[7]); \
    r2[4][5] = S27*(mx[8]*sv[6] + mx[6]*sv[8]) - S37*mx[7]*sv[7];

// ---------------- kernel A: vmp + node-CG + wn mix -> mixed[256][72] -------
// block 0 also zeroes psum[3] (runs strictly before k_pair in stream order).
__global__ __launch_bounds__(256) void k_nodes(
                        const float* __restrict__ adj,
                        const float* __restrict__ v0,
                        const float* __restrict__ v1,
                        const float* __restrict__ v2,
                        const float* __restrict__ wn0,
                        const float* __restrict__ wn1,
                        const float* __restrict__ wn2,
                        float* __restrict__ mixed,
                        float* __restrict__ psum){
  __shared__ float part[4][72];
  int i = blockIdx.x;
  int tid = threadIdx.x, wv = tid >> 6, lane = tid & 63;
  if (i == 0 && tid < 3) psum[tid] = 0.f;
  {
    const float* vp1; int st1;
    if (lane < 8)       { vp1 = v0 + lane;      st1 = 8;  }
    else if (lane < 32) { vp1 = v1 + (lane-8);  st1 = 24; }
    else                { vp1 = v2 + (lane-32); st1 = 40; }
    const float* vp2 = v2 + 32 + lane;
    const float* arow = adj + i*NN;
    int j0 = wv*64;
    float a1a = 0.f, a1b = 0.f, a2a = 0.f, a2b = 0.f;
    #pragma unroll 8
    for (int j = j0; j < j0+64; j += 2){
      float av0 = arow[j], av1 = arow[j+1];
      a1a = fmaf(av0, vp1[j*st1], a1a);
      a1b = fmaf(av1, vp1[(j+1)*st1], a1b);
      if (lane < 8){
        a2a = fmaf(av0, vp2[j*40], a2a);
        a2b = fmaf(av1, vp2[(j+1)*40], a2b);
      }
    }
    part[wv][lane] = a1a + a1b;
    if (lane < 8) part[wv][64+lane] = a2a + a2b;
  }
  __syncthreads();
  if (wv) return;
  {
    float s = part[0][lane] + part[1][lane] + part[2][lane] + part[3][lane];
    float s2 = 0.f;
    if (lane < 8)
      s2 = part[0][64+lane] + part[1][64+lane] + part[2][64+lane] + part[3][64+lane];
    part[0][lane] = s;
    if (lane < 8) part[0][64+lane] = s2;
  }
  int c = lane >> 3, d = lane & 7;
  float mx[9], sv[9];
  #pragma unroll
  for (int j=0;j<9;j++){ mx[j] = part[0][j*8 + c]; sv[j] = part[0][j*8 + d]; }
  float r0[3], r1[3][6], r2[5][6];
  CGREL(mx, sv, r0, r1, r2)

  float a0[8], a1m[3][8], a2m[5][8];
  #pragma unroll
  for (int dp=0;dp<8;dp++){ a0[dp]=0.f;
    #pragma unroll
    for (int M=0;M<3;M++) a1m[M][dp]=0.f;
    #pragma unroll
    for (int M=0;M<5;M++) a2m[M][dp]=0.f;
  }
  #pragma unroll
  for (int k=0;k<3;k++){
    const float* row = wn0 + (k*64 + lane)*8;
    float4 u = *(const float4*)row;
    float4 v = *(const float4*)(row+4);
    float u8[8] = {u.x,u.y,u.z,u.w,v.x,v.y,v.z,v.w};
    #pragma unroll
    for (int dp=0;dp<8;dp++) a0[dp] = fmaf(r0[k], u8[dp], a0[dp]);
  }
  #pragma unroll
  for (int k=0;k<6;k++){
    const float* row = wn1 + (k*64 + lane)*8;
    float4 u = *(const float4*)row;
    float4 v = *(const float4*)(row+4);
    float u8[8] = {u.x,u.y,u.z,u.w,v.x,v.y,v.z,v.w};
    #pragma unroll
    for (int M=0;M<3;M++)
      #pragma unroll
      for (int dp=0;dp<8;dp++) a1m[M][dp] = fmaf(r1[M][k], u8[dp], a1m[M][dp]);
  }
  #pragma unroll
  for (int k=0;k<6;k++){
    const float* row = wn2 + (k*64 + lane)*8;
    float4 u = *(const float4*)row;
    float4 v = *(const float4*)(row+4);
    float u8[8] = {u.x,u.y,u.z,u.w,v.x,v.y,v.z,v.w};
    #pragma unroll
    for (int M=0;M<5;M++)
      #pragma unroll
      for (int dp=0;dp<8;dp++) a2m[M][dp] = fmaf(r2[M][k], u8[dp], a2m[M][dp]);
  }
  #pragma unroll
  for (int m=0;m<9;m++){
    #pragma unroll
    for (int dp=0;dp<8;dp++){
      float val = (m==0) ? a0[dp] : (m<4 ? a1m[m-1][dp] : a2m[m-4][dp]);
      val += __shfl_xor(val, 1);
      val += __shfl_xor(val, 2);
      val += __shfl_xor(val, 4);
      val += __shfl_xor(val, 8);
      val += __shfl_xor(val, 16);
      val += __shfl_xor(val, 32);
      if (lane == ((m*8+dp) & 63)) mixed[i*72 + m*8 + dp] = val;
    }
  }
}

// ---------------- kernel B: pairwise CG + wr mix -> per-block partials -----
// 2048 blocks x 4 waves. nt wr loads. No atomics into vsum: block (y,xsel)
// overwrites part[(xsel*NN+y)*72 + t]. Part sums via 3 atomics/block.
__global__ __launch_bounds__(256) void k_pair(
    const float* __restrict__ mixed,
    const float* __restrict__ s0, const float* __restrict__ s1, const float* __restrict__ s2,
    const float* __restrict__ wr0, const float* __restrict__ wr1, const float* __restrict__ wr2,
    float* __restrict__ part, float* __restrict__ psum){
  __shared__ float red[4][72];
  __shared__ float bp[3];
  int tid = threadIdx.x;
  int wv = tid >> 6, lane = tid & 63;
  int y = blockIdx.x & (NN-1);
  int xsel = blockIdx.x >> 8;              // 0..7
  int xbase = (xsel*4 + wv) * XPW;
  int cgp = lane >> 3;

  float acc[9];
  #pragma unroll
  for (int m=0;m<9;m++) acc[m]=0.f;

  for (int i=0;i<XPW;i++){
    int x = xbase + i;
    int pxy = x*NN + y;
    const float* p0 = wr0 + (size_t)pxy*192 + lane;
    const float* p1 = wr1 + (size_t)pxy*384 + lane;
    const float* p2 = wr2 + (size_t)pxy*384 + lane;
    float w0v[3], w1v[6], w2v[6];
    #pragma unroll
    for (int k=0;k<3;k++) w0v[k] = __builtin_nontemporal_load(p0 + k*64);
    #pragma unroll
    for (int k=0;k<6;k++) w1v[k] = __builtin_nontemporal_load(p1 + k*64);
    #pragma unroll
    for (int k=0;k<6;k++) w2v[k] = __builtin_nontemporal_load(p2 + k*64);

    float mx[9], sv[9];
    {
      const float* mb = mixed + x*72 + cgp;
      #pragma unroll
      for (int j=0;j<9;j++) mx[j] = mb[j*8];
      sv[0] = s0[pxy];
      #pragma unroll
      for (int j=0;j<3;j++) sv[1+j] = s1[(size_t)pxy*3+j];
      #pragma unroll
      for (int j=0;j<5;j++) sv[4+j] = s2[(size_t)pxy*5+j];
    }

    float r0[3], r1[3][6], r2[5][6];
    CGREL(mx, sv, r0, r1, r2)

    #pragma unroll
    for (int k=0;k<3;k++) acc[0] = fmaf(r0[k], w0v[k], acc[0]);
    #pragma unroll
    for (int k=0;k<6;k++){
      acc[1] = fmaf(r1[0][k], w1v[k], acc[1]);
      acc[2] = fmaf(r1[1][k], w1v[k], acc[2]);
      acc[3] = fmaf(r1[2][k], w1v[k], acc[3]);
      acc[4] = fmaf(r2[0][k], w2v[k], acc[4]);
      acc[5] = fmaf(r2[1][k], w2v[k], acc[5]);
      acc[6] = fmaf(r2[2][k], w2v[k], acc[6]);
      acc[7] = fmaf(r2[3][k], w2v[k], acc[7]);
      acc[8] = fmaf(r2[4][k], w2v[k], acc[8]);
    }
  }

  // reduce over cgp groups (lane bits 3..5)
  #pragma unroll
  for (int m=0;m<9;m++){
    float v = acc[m];
    v += __shfl_xor(v, 8);
    v += __shfl_xor(v, 16);
    v += __shfl_xor(v, 32);
    acc[m] = v;
  }
  if (lane < 8){
    #pragma unroll
    for (int m=0;m<9;m++) red[wv][m*8+lane] = acc[m];
  }
  if (tid < 3) bp[tid] = 0.f;
  __syncthreads();
  if (tid < 72){
    float v = red[0][tid] + red[1][tid] + red[2][tid] + red[3][tid];
    part[((size_t)xsel*NN + y)*72 + tid] = v;
    int mall = tid >> 3;
    int l = (mall==0) ? 0 : (mall < 4 ? 1 : 2);
    atomicAdd(&bp[l], v);
  }
  __syncthreads();
  if (tid < 3) atomicAdd(&psum[tid], bp[tid]);
}

// ---------------- kernel C: gather partials + normalize + write ------------
__global__ __launch_bounds__(256) void k_final(
    const float* __restrict__ part, const float* __restrict__ psum,
    float* __restrict__ out){
  int idx = blockIdx.x*256 + threadIdx.x;   // 72 blocks -> 18432 exactly
  int y = idx / 72;
  int t = idx - y*72;
  float v = 0.f;
  #pragma unroll
  for (int x=0; x<NXS; x++) v += part[((size_t)x*NN + y)*72 + t];
  int mall = t >> 3;
  float den = (mall == 0) ? psum[0] : (mall < 4 ? psum[1] : psum[2]);
  out[idx] = v / den;
}

extern "C" void kernel_launch(void* const* d_in, const int* in_sizes, int n_in,
                              void* d_out, int out_size, void* d_ws, size_t ws_size,
                              hipStream_t stream) {
  const float* v0  = (const float*)d_in[0];
  const float* v1  = (const float*)d_in[1];
  const float* v2  = (const float*)d_in[2];
  const float* adj = (const float*)d_in[3];
  const float* s0  = (const float*)d_in[4];
  const float* s1  = (const float*)d_in[5];
  const float* s2  = (const float*)d_in[6];
  const float* wn0 = (const float*)d_in[7];
  const float* wn1 = (const float*)d_in[8];
  const float* wn2 = (const float*)d_in[9];
  const float* wr0 = (const float*)d_in[10];
  const float* wr1 = (const float*)d_in[11];
  const float* wr2 = (const float*)d_in[12];
  float* out = (float*)d_out;

  float* ws    = (float*)d_ws;
  float* mixed = ws;                       // 18432
  float* part  = ws + 18432;               // NXS*256*72 = 147456
  float* psum  = ws + 18432 + 147456;      // 3

  k_nodes<<<NN, 256, 0, stream>>>(adj, v0, v1, v2, wn0, wn1, wn2, mixed, psum);
  k_pair<<<NN*NXS, 256, 0, stream>>>(mixed, s0, s1, s2, wr0, wr1, wr2, part, psum);
  k_final<<<72, 256, 0, stream>>>(part, psum, out);
}